// Round 3
// baseline (1115.053 us; speedup 1.0000x reference)
//
#include <hip/hip_runtime.h>

#define LROW    2904
#define PERIOD  24
#define CYC     121          // LROW / PERIOD (odd -> median = 0-indexed rank 60)
#define NT      256
#define NROWS   13248        // 64 * 207
#define CHUNK   (NROWS / 8)
#define NPASS   4            // 4 x 5-bit radix passes -> 20-bit prefix
#define HISTPAD 25           // 32 bins x 25 (pad) -> bank-conflict-free column reads

__device__ __forceinline__ int clampi(int i) {
    return i < 0 ? 0 : (i >= LROW ? LROW - 1 : i);
}

// order-preserving uint mapping of float, and inverse
__device__ __forceinline__ unsigned sortable(float x) {
    unsigned u = __float_as_uint(x);
    return u ^ ((unsigned)((int)u >> 31) | 0x80000000u);
}
__device__ __forceinline__ float unsortable(unsigned k) {
    unsigned u = ((int)k >= 0) ? ~k : (k ^ 0x80000000u);
    return __uint_as_float(u);
}

// SA[l] = sum_{j=-6..6} A[clamp(l+j)]  (raw sum, not divided)
__device__ __forceinline__ void build_sa(const float* A, float* SAb, int t) {
    int l0 = t * 13;
    if (l0 >= LROW) return;
    int l1 = min(l0 + 13, LROW);
    float sum = 0.f;
    #pragma unroll
    for (int j = -6; j <= 6; ++j) sum += A[clampi(l0 + j)];
    SAb[l0] = sum;
    for (int l = l0 + 1; l < l1; ++l) {
        sum += A[clampi(l + 6)] - A[clampi(l - 7)];
        SAb[l] = sum;
    }
}

// sum_{j=-6..6} lmed[phase(clamp(l+j))] for edge l (l<6 or l>=LROW-6)
__device__ __forceinline__ float ws_edge(int l, const float* lmed) {
    float w = 0.f;
    #pragma unroll
    for (int j = -6; j <= 6; ++j) {
        int idx = clampi(l + j);
        int ph = (idx < PERIOD) ? idx : idx - 2880;   // 2880 = 120*24; valid at edges
        w += lmed[ph];
    }
    return w;
}

__global__ __launch_bounds__(NT, 6) void stl_kernel(const float* __restrict__ x,
                                                    float* __restrict__ out) {
    __shared__ float    A[LROW];           // input row s
    __shared__ float    SAb[LROW];         // window-13 clamped sliding sum of s
    __shared__ unsigned hist[32 * HISTPAD];
    __shared__ float    lmed[PERIOD];      // seasonal (24 medians)
    __shared__ float    Wtab[PERIOD];      // Wtab[p] = sum_{j=0..12} lmed[(p+j)%24]
    __shared__ unsigned sprefix[PERIOD];   // radix prefix per phase

    // chunked XCD swizzle (bijective: NROWS % 8 == 0): adjacent rows -> same L2
    const int d   = blockIdx.x;
    const int row = (d & 7) * CHUNK + (d >> 3);
    const int b = row / 207;
    const int f = row - b * 207;
    const int t = threadIdx.x;
    const size_t rowbase = (size_t)b * (LROW * 207) + (size_t)f;

    for (int l = t; l < LROW; l += NT) A[l] = x[rowbase + (size_t)l * 207];
    __syncthreads();

    build_sa(A, SAb, t);
    __syncthreads();

    const int p   = t >> 3;    // phase owned by median threads (t < 192)
    const int sub = t & 7;     // sub-slot: owns cycles c = sub + 8k

    for (int iter = 0; iter < 2; ++iter) {
        // ---- build this iteration's keys into registers (trend on the fly)
        unsigned kreg[16];
        if (t < 192) {
            float wph = (iter == 1) ? Wtab[(p + 18) % 24] : 0.f;  // (p-6) mod 24
            #pragma unroll
            for (int k = 0; k < 16; ++k) {
                int c = sub + 8 * k;
                if (c < CYC) {
                    int l = c * PERIOD + p;
                    float w = wph;
                    if (iter == 1) {                     // only sub==0 can diverge
                        if (c == 0 && p < 6)        w = ws_edge(l, lmed);
                        else if (c == 120 && p >= 18) w = ws_edge(l, lmed);
                    }
                    float tr = (SAb[l] - w) * (1.f / 13.f);
                    kreg[k] = sortable(A[l] - tr);
                }
            }
        }

        // ---- 4 x 5-bit MSB radix select of rank 60, per phase
        int r = 60;                                // live in binfind lanes (t<24)
        for (int pass = 0; pass < NPASS; ++pass) {
            for (int i = t; i < 32 * HISTPAD; i += NT) hist[i] = 0;
            __syncthreads();
            if (t < 192) {
                unsigned pref = (pass == 0) ? 0u : sprefix[p];
                int bsh = 27 - 5 * pass;
                #pragma unroll
                for (int k = 0; k < 16; ++k) {
                    int c = sub + 8 * k;
                    if (c < CYC) {
                        unsigned key = kreg[k];
                        bool match = (pass == 0) || ((key >> (bsh + 5)) == pref);
                        if (match) {
                            unsigned bin = (key >> bsh) & 31u;
                            atomicAdd(&hist[bin * HISTPAD + p], 1u);
                        }
                    }
                }
            }
            __syncthreads();
            if (t < PERIOD) {
                unsigned cum = 0, below = 0; int sel = -1;
                for (int bb = 0; bb < 32; ++bb) {
                    unsigned c = hist[bb * HISTPAD + t];
                    if (sel < 0 && cum + c > (unsigned)r) { sel = bb; below = cum; }
                    cum += c;
                }
                r -= (int)below;
                sprefix[t] = (pass == 0) ? (unsigned)sel
                                         : ((sprefix[t] << 5) | (unsigned)sel);
            }
            __syncthreads();
        }

        // ---- reconstruct medians (bucket midpoint) + window-sum table
        if (t < PERIOD) {
            lmed[t] = unsortable((sprefix[t] << 12) | 0x800u);
            float w = 0.f;
            #pragma unroll
            for (int j = 0; j < 13; ++j) {
                int ph = t + j; if (ph >= PERIOD) ph -= PERIOD;
                w += lmed[ph];       // same-wave LDS writes visible in order
            }
            Wtab[t] = w;
        }
        __syncthreads();
    }

    // ---- outputs: trend, seasonal, residual ([B,L,F] each, concatenated)
    const size_t S = (size_t)NROWS * LROW;
    {
        int l = t;
        int ph = t % PERIOD;
        while (l < LROW) {
            float w;
            if (l < 6 || l >= LROW - 6) w = ws_edge(l, lmed);
            else { int p6 = ph - 6; if (p6 < 0) p6 += PERIOD; w = Wtab[p6]; }
            float tr = (SAb[l] - w) * (1.f / 13.f);
            float se = lmed[ph];
            float re = A[l] - tr - se;
            size_t o = rowbase + (size_t)l * 207;
            out[o]         = tr;
            out[S + o]     = se;
            out[2 * S + o] = re;
            l += NT;
            ph += 16; if (ph >= PERIOD) ph -= PERIOD;
        }
    }
}

extern "C" void kernel_launch(void* const* d_in, const int* in_sizes, int n_in,
                              void* d_out, int out_size, void* d_ws, size_t ws_size,
                              hipStream_t stream) {
    const float* x = (const float*)d_in[0];
    float* out = (float*)d_out;
    (void)in_sizes; (void)n_in; (void)out_size; (void)d_ws; (void)ws_size;
    hipLaunchKernelGGL(stl_kernel, dim3(NROWS), dim3(NT), 0, stream, x, out);
}

// Round 4
// 612.307 us; speedup vs baseline: 1.8211x; 1.8211x over previous
//
#include <hip/hip_runtime.h>

#define LROW    2904
#define PERIOD  24
#define CYC     121          // LROW / PERIOD (odd -> median = 0-indexed rank 60)
#define NT      256
#define NF      207
#define NB      64
#define NROWS   13248        // NB * NF
#define CHUNK   (NROWS / 8)
#define LTILE   24
#define NLT     (LROW / LTILE)   // 121
#define K2GRID  (NB * NLT)       // 7744 = 8 * 968
#define K2CHUNK (K2GRID / 8)
#define NPASS   4            // 4 x 5-bit radix passes -> 20-bit prefix
#define HISTPAD 25

__device__ __forceinline__ int clampi(int i) {
    return i < 0 ? 0 : (i >= LROW ? LROW - 1 : i);
}
__device__ __forceinline__ unsigned sortable(float x) {
    unsigned u = __float_as_uint(x);
    return u ^ ((unsigned)((int)u >> 31) | 0x80000000u);
}
__device__ __forceinline__ float unsortable(unsigned k) {
    unsigned u = ((int)k >= 0) ? ~k : (k ^ 0x80000000u);
    return __uint_as_float(u);
}

// SA[l] = sum_{j=-6..6} A[clamp(l+j)]
__device__ __forceinline__ void build_sa(const float* A, float* SAb, int t) {
    int l0 = t * 13;
    if (l0 >= LROW) return;
    int l1 = min(l0 + 13, LROW);
    float sum = 0.f;
    #pragma unroll
    for (int j = -6; j <= 6; ++j) sum += A[clampi(l0 + j)];
    SAb[l0] = sum;
    for (int l = l0 + 1; l < l1; ++l) {
        sum += A[clampi(l + 6)] - A[clampi(l - 7)];
        SAb[l] = sum;
    }
}

__device__ __forceinline__ float ws_edge(int l, const float* lmed) {
    float w = 0.f;
    #pragma unroll
    for (int j = -6; j <= 6; ++j) {
        int idx = clampi(l + j);
        int ph = (idx < PERIOD) ? idx : idx - 2880;
        w += lmed[ph];
    }
    return w;
}

// ================= Kernel 1: per-row medians + window-sum table ============
__global__ __launch_bounds__(NT, 6) void stl_medians(const float* __restrict__ x,
                                                     float* __restrict__ ws) {
    __shared__ float    A[LROW];
    __shared__ float    SAb[LROW];
    __shared__ unsigned hist[32 * HISTPAD];
    __shared__ float    lmed[PERIOD];
    __shared__ float    Wtab[PERIOD];
    __shared__ unsigned sprefix[PERIOD];

    const int d   = blockIdx.x;
    const int row = (d & 7) * CHUNK + (d >> 3);    // bijective XCD swizzle
    const int b = row / NF;
    const int f = row - b * NF;
    const int t = threadIdx.x;
    const size_t rowbase = (size_t)b * (LROW * NF) + (size_t)f;

    for (int l = t; l < LROW; l += NT) A[l] = x[rowbase + (size_t)l * NF];
    __syncthreads();
    build_sa(A, SAb, t);
    __syncthreads();

    const int p   = t >> 3;
    const int sub = t & 7;

    for (int iter = 0; iter < 2; ++iter) {
        unsigned kreg[16];
        if (t < 192) {
            float wph = (iter == 1) ? Wtab[(p + 18) % 24] : 0.f;
            #pragma unroll
            for (int k = 0; k < 16; ++k) {
                int c = sub + 8 * k;
                if (c < CYC) {
                    int l = c * PERIOD + p;
                    float w = wph;
                    if (iter == 1) {
                        if (c == 0 && p < 6)          w = ws_edge(l, lmed);
                        else if (c == 120 && p >= 18) w = ws_edge(l, lmed);
                    }
                    float tr = (SAb[l] - w) * (1.f / 13.f);
                    kreg[k] = sortable(A[l] - tr);
                }
            }
        }

        int r = 60;
        for (int pass = 0; pass < NPASS; ++pass) {
            for (int i = t; i < 32 * HISTPAD; i += NT) hist[i] = 0;
            __syncthreads();
            if (t < 192) {
                unsigned pref = (pass == 0) ? 0u : sprefix[p];
                int bsh = 27 - 5 * pass;
                #pragma unroll
                for (int k = 0; k < 16; ++k) {
                    int c = sub + 8 * k;
                    if (c < CYC) {
                        unsigned key = kreg[k];
                        bool match = (pass == 0) || ((key >> (bsh + 5)) == pref);
                        if (match)
                            atomicAdd(&hist[((key >> bsh) & 31u) * HISTPAD + p], 1u);
                    }
                }
            }
            __syncthreads();
            if (t < PERIOD) {
                unsigned cum = 0, below = 0; int sel = -1;
                for (int bb = 0; bb < 32; ++bb) {
                    unsigned c = hist[bb * HISTPAD + t];
                    if (sel < 0 && cum + c > (unsigned)r) { sel = bb; below = cum; }
                    cum += c;
                }
                r -= (int)below;
                sprefix[t] = (pass == 0) ? (unsigned)sel
                                         : ((sprefix[t] << 5) | (unsigned)sel);
            }
            __syncthreads();
        }

        if (t < PERIOD) {
            lmed[t] = unsortable((sprefix[t] << 12) | 0x800u);
            float w = 0.f;
            #pragma unroll
            for (int j = 0; j < 13; ++j) {
                int ph = t + j; if (ph >= PERIOD) ph -= PERIOD;
                w += lmed[ph];
            }
            Wtab[t] = w;
        }
        __syncthreads();
    }

    // ws layout [b][48][f]: i<24 -> lmed, i>=24 -> Wtab (coalesced reads in K2)
    if (t < PERIOD) {
        ws[((size_t)b * 48 + t) * NF + f]          = lmed[t];
        ws[((size_t)b * 48 + 24 + t) * NF + f]     = Wtab[t];
    }
}

// ================= Kernel 2: coalesced output generation ===================
__global__ __launch_bounds__(NT, 5) void stl_outputs(const float* __restrict__ x,
                                                     const float* __restrict__ ws,
                                                     float* __restrict__ out) {
    __shared__ float T[(LTILE + 12) * NF];   // rows l0-6 .. l0+29, f-major

    const int d   = blockIdx.x;
    const int blk = (d & 7) * K2CHUNK + (d >> 3);  // bijective XCD swizzle
    const int b  = blk / NLT;
    const int kk = blk - b * NLT;
    const int l0 = kk * LTILE;
    const int t  = threadIdx.x;
    const float* xb = x + (size_t)b * (LROW * NF);

    if (kk != 0 && kk != NLT - 1) {
        // interior: contiguous copy; (l0-6)*NF is always even -> float2 aligned
        const float2* s2 = (const float2*)(xb + (size_t)(l0 - 6) * NF);
        float2* t2 = (float2*)T;
        for (int i = t; i < (LTILE + 12) * NF / 2; i += NT) t2[i] = s2[i];
    } else {
        for (int i = t; i < (LTILE + 12) * NF; i += NT) {
            int lr = i / NF;
            int ff = i - lr * NF;
            int l  = clampi(l0 - 6 + lr);
            T[i] = xb[(size_t)l * NF + ff];
        }
    }
    __syncthreads();

    if (t < NF) {
        float lm[PERIOD], wt[PERIOD];
        const float* wrow = ws + (size_t)b * 48 * NF + t;
        #pragma unroll
        for (int i = 0; i < PERIOD; ++i) lm[i] = wrow[i * NF];
        #pragma unroll
        for (int i = 0; i < PERIOD; ++i) wt[i] = wrow[(PERIOD + i) * NF];

        float s13 = 0.f;
        #pragma unroll
        for (int r = 0; r < 13; ++r) s13 += T[r * NF + t];

        const bool edgeLo = (kk == 0), edgeHi = (kk == NLT - 1);
        const size_t S = (size_t)NROWS * LROW;
        const size_t obase = (size_t)b * (LROW * NF) + (size_t)l0 * NF + (size_t)t;

        #pragma unroll
        for (int j = 0; j < LTILE; ++j) {
            float W = wt[(j + 18) % 24];
            if (edgeLo && j < 6) {
                float w = 0.f;
                #pragma unroll
                for (int jj = -6; jj <= 6; ++jj) { int m = j + jj; if (m < 0) m = 0; w += lm[m]; }
                W = w;
            }
            if (edgeHi && j >= 18) {
                float w = 0.f;
                #pragma unroll
                for (int jj = -6; jj <= 6; ++jj) { int m = j + jj; if (m > 23) m = 23; w += lm[m]; }
                W = w;
            }
            float tr = (s13 - W) * (1.f / 13.f);
            float se = lm[j];
            float re = T[(j + 6) * NF + t] - tr - se;
            size_t o = obase + (size_t)(j * NF);
            out[o]         = tr;
            out[S + o]     = se;
            out[2 * S + o] = re;
            if (j < LTILE - 1)
                s13 += T[(j + 13) * NF + t] - T[j * NF + t];
        }
    }
}

extern "C" void kernel_launch(void* const* d_in, const int* in_sizes, int n_in,
                              void* d_out, int out_size, void* d_ws, size_t ws_size,
                              hipStream_t stream) {
    const float* x = (const float*)d_in[0];
    float* out = (float*)d_out;
    float* ws  = (float*)d_ws;     // needs NB*48*NF*4 = 2.55 MB
    (void)in_sizes; (void)n_in; (void)out_size; (void)ws_size;
    hipLaunchKernelGGL(stl_medians, dim3(NROWS), dim3(NT), 0, stream, x, ws);
    hipLaunchKernelGGL(stl_outputs, dim3(K2GRID), dim3(NT), 0, stream, x, ws, out);
}